// Round 1
// 211.129 us; speedup vs baseline: 1.0189x; 1.0189x over previous
//
#include <hip/hip_runtime.h>
#include <hip/hip_bf16.h>

// Problem constants
constexpr int BB = 2;
constexpr int SS = 2048;
constexpr int EE = 1024;
constexpr int HH = 16;
constexpr int DD = 64;
constexpr int MM = BB * SS;              // 4096 rows in the projection GEMMs
constexpr int CX = MM * EE;              // 4194304 elems per X slice (2^22)
constexpr int CW = EE * EE;              // 1048576 elems per W slice (2^20)
// Q pre-scale: 1/sqrt(EMBED_DIM) * log2(e) so attention scores are base-2 logits
#define QSCALE 0.045084220027780106f

typedef __attribute__((ext_vector_type(8))) short short8;    // 8 bf16 = 4 VGPRs (MFMA A/B frag)
typedef __attribute__((ext_vector_type(4))) float floatx4;   // MFMA C/D frag

__device__ inline short bf16bits(float x) {
    __hip_bfloat16 h = __float2bfloat16(x);
    return *reinterpret_cast<short*>(&h);
}

__device__ inline unsigned pkbf(float a, float b) {
    return (unsigned)(unsigned short)bf16bits(a) |
           ((unsigned)(unsigned short)bf16bits(b) << 16);
}

__device__ inline float fast_exp2(float x) {
#if __has_builtin(__builtin_amdgcn_exp2f)
    return __builtin_amdgcn_exp2f(x);
#else
    return exp2f(x);
#endif
}

// Async global->LDS, 16 B per lane. LDS dest = wave-uniform base + lane*16.
__device__ inline void gl_lds16(const __hip_bfloat16* g, const short* l) {
    __builtin_amdgcn_global_load_lds(
        (const __attribute__((address_space(1))) void*)g,
        (__attribute__((address_space(3))) void*)l, 16, 0, 0);
}

// ---------------------------------------------------------------------------
// Convert pass: f32 -> bf16, flat over 3 X slices then 3 W slices. (unchanged)
// ---------------------------------------------------------------------------
__global__ __launch_bounds__(256) void convert_kernel(
    const float* __restrict__ x0, const float* __restrict__ x1, const float* __restrict__ x2,
    const float* __restrict__ w0, const float* __restrict__ w1, const float* __restrict__ w2,
    __hip_bfloat16* __restrict__ xb, __hip_bfloat16* __restrict__ wb)
{
    const long long e = (long long)(blockIdx.x * 256 + threadIdx.x) * 8;
    const float* src;
    __hip_bfloat16* dst;
    if (e < 3LL * CX) {
        const int z = (int)(e >> 22);
        const int off = (int)(e & (CX - 1));
        src = ((z == 0) ? x0 : (z == 1) ? x1 : x2) + off;
        dst = xb + e;
    } else {
        const long long e2 = e - 3LL * CX;
        const int z = (int)(e2 >> 20);
        const int off = (int)(e2 & (CW - 1));
        src = ((z == 0) ? w0 : (z == 1) ? w1 : w2) + off;
        dst = wb + e2;
    }
    const float4 a = reinterpret_cast<const float4*>(src)[0];
    const float4 b = reinterpret_cast<const float4*>(src)[1];
    short8 r;
    r[0] = bf16bits(a.x); r[1] = bf16bits(a.y); r[2] = bf16bits(a.z); r[3] = bf16bits(a.w);
    r[4] = bf16bits(b.x); r[5] = bf16bits(b.y); r[6] = bf16bits(b.z); r[7] = bf16bits(b.w);
    *reinterpret_cast<short8*>(dst) = r;
}

// ---------------------------------------------------------------------------
// Projection GEMM (unchanged, best measured): 128x128 tile, BK=32,
// 256 threads, 2-barrier K-loop, async global_load_lds, superrow swizzle.
// which==0 output (Q) pre-scaled by QSCALE. V stored transposed [B,H,D,S].
// ---------------------------------------------------------------------------
__global__ __launch_bounds__(256) void proj_gemm(
    const __hip_bfloat16* __restrict__ xb,
    const __hip_bfloat16* __restrict__ wb,
    const float* __restrict__ bq, const float* __restrict__ bk, const float* __restrict__ bv,
    __hip_bfloat16* __restrict__ qws,
    __hip_bfloat16* __restrict__ kws,
    __hip_bfloat16* __restrict__ vtws)
{
    const int which = blockIdx.z;
    const __hip_bfloat16* A = xb + (size_t)which * CX;
    const __hip_bfloat16* W = wb + (size_t)which * CW;
    const float* bias = (which == 0) ? bq : (which == 1) ? bk : bv;

    const int m0   = blockIdx.x * 128;
    const int n0   = blockIdx.y * 128;
    const int tid  = threadIdx.x;
    const int wave = tid >> 6;
    const int lane = tid & 63;
    const int l15  = lane & 15;
    const int quad = lane >> 4;
    const int wr   = wave >> 1;
    const int wc   = wave & 1;

    __shared__ __align__(16) short As[128 * 32];   // 8 KiB, superrow-swizzled
    __shared__ __align__(16) short Bs[128 * 32];   // 8 KiB

    const int dpos  = (lane & 7) ^ (lane >> 3);
    const int drloc = 2 * (lane >> 3) + (dpos >> 2);
    const int dgran = (dpos & 3) * 8;              // k-offset in shorts

    const int rbase = (l15 >> 1) * 64;             // superrow offset within tile
    const int rslot = (((l15 & 1) * 4 + quad) ^ (l15 >> 1)) * 8;

    floatx4 acc[4][4] = {};

    for (int k0 = 0; k0 < EE; k0 += 32) {
        __syncthreads();  // WAR: previous iteration's frag reads complete
        #pragma unroll
        for (int p = 0; p < 2; ++p) {
            const int rb16 = wave * 32 + p * 16;   // 16-row issue base
            gl_lds16(A + (size_t)(m0 + rb16 + drloc) * EE + k0 + dgran, &As[rb16 * 32]);
            gl_lds16(W + (size_t)(n0 + rb16 + drloc) * EE + k0 + dgran, &Bs[rb16 * 32]);
        }
        __syncthreads();  // staging visible (drains vmcnt)

        short8 af[4], bf[4];
        #pragma unroll
        for (int mt = 0; mt < 4; ++mt)
            af[mt] = *reinterpret_cast<const short8*>(
                &As[(wr * 32 + mt * 8) * 64 + rbase + rslot]);
        #pragma unroll
        for (int nt = 0; nt < 4; ++nt)
            bf[nt] = *reinterpret_cast<const short8*>(
                &Bs[(wc * 32 + nt * 8) * 64 + rbase + rslot]);

        #pragma unroll
        for (int mt = 0; mt < 4; ++mt)
            #pragma unroll
            for (int nt = 0; nt < 4; ++nt)
                acc[mt][nt] = __builtin_amdgcn_mfma_f32_16x16x32_bf16(af[mt], bf[nt], acc[mt][nt], 0, 0, 0);
    }

    // Epilogue: C/D layout col = lane&15, row = quad*4 + r
    #pragma unroll
    for (int nt = 0; nt < 4; ++nt) {
        const int n = n0 + wc * 64 + nt * 16 + l15;
        const float bval = bias[n];
        const int h = n >> 6, d = n & 63;
        #pragma unroll
        for (int mt = 0; mt < 4; ++mt) {
            #pragma unroll
            for (int r = 0; r < 4; ++r) {
                const int m = m0 + wr * 64 + mt * 16 + quad * 4 + r;
                const int b = m >> 11;
                const int s = m & (SS - 1);
                float val = acc[mt][nt][r] + bval;
                if (which == 0) val *= QSCALE;   // fold softmax scale+log2e into Q
                const __hip_bfloat16 hv = __float2bfloat16(val);
                if (which == 0)
                    qws[(((size_t)b * HH + h) * SS + s) * DD + d] = hv;
                else if (which == 1)
                    kws[(((size_t)b * HH + h) * SS + s) * DD + d] = hv;
                else
                    vtws[(((size_t)b * HH + h) * DD + d) * SS + s] = hv;
            }
        }
    }
}

// ---------------------------------------------------------------------------
// Flash attention v2: 32 q-rows/wave (128 q/block, grid 512, 2 blocks/CU),
// double-buffered K/V DMA staging with a 1-barrier counted pipeline
// (prefetch issued at loop top, vmcnt(0)+raw s_barrier at loop bottom so
// the DMA flies under QK/softmax/PV), mask pre-staged to LDS as {0,1}
// floats (broadcast reads, applied as post-exp2 multiply — no in-loop
// global loads polluting the vmem queue). Each K/V fragment read from LDS
// now feeds 2 MFMAs (two q column blocks) -> LDS bytes per q-row drop ~40%.
// XCD-aware block swizzle as before: XCD c serves heads {4c..4c+3}
// (~2 MB K+VT working set fits the 4 MB per-XCD L2).
// ---------------------------------------------------------------------------
__global__ __launch_bounds__(256) void attn_kernel(
    const __hip_bfloat16* __restrict__ qws,
    const __hip_bfloat16* __restrict__ kws,
    const __hip_bfloat16* __restrict__ vtws,
    const int* __restrict__ amask,
    float* __restrict__ out)
{
    const int flatb = blockIdx.y * gridDim.x + blockIdx.x;     // 0..511
    const int bh    = 4 * (flatb & 7) + ((flatb >> 3) & 3);    // XCD-partitioned head
    const int b     = bh >> 4;
    const int q0    = (flatb >> 5) * 128;
    const int tid  = threadIdx.x;
    const int wave = tid >> 6;
    const int lane = tid & 63;
    const int l15  = lane & 15;
    const int quad = lane >> 4;

    const __hip_bfloat16* Q  = qws  + (size_t)bh * SS * DD;
    const __hip_bfloat16* K  = kws  + (size_t)bh * SS * DD;
    const __hip_bfloat16* VT = vtws + (size_t)bh * DD * SS;
    const int* msk = amask + b * SS;

    __shared__ __align__(16) short Ks[2][64 * 64];   // 16 KiB, [key][d] swizzled, dbuf
    __shared__ __align__(16) short Vs[2][64 * 64];   // 16 KiB, [d][key] swizzled, dbuf
    __shared__ __align__(16) short Ps[4][32 * 64];   // 16 KiB, per-wave P[q][key] swizzled
    __shared__ __align__(16) float Ms[SS];           // 8 KiB, mask as {0,1} floats
    short* pw0 = Ps[wave];
    short* pw1 = Ps[wave] + 16 * 64;

    // Stage mask once: int {0,1} -> float {0,1} (multiplied in post-exp2)
    #pragma unroll
    for (int i = 0; i < 2; ++i) {
        const int j = tid + i * 256;
        const int4 m4 = reinterpret_cast<const int4*>(msk)[j];
        float4 f4;
        f4.x = (float)m4.x; f4.y = (float)m4.y; f4.z = (float)m4.z; f4.w = (float)m4.w;
        reinterpret_cast<float4*>(Ms)[j] = f4;
    }

    // Q fragments for two 16-row column blocks (32 q-rows per wave), in regs
    const int qrow = q0 + wave * 32 + l15;
    const short8 qa0 = *reinterpret_cast<const short8*>(Q + (size_t)qrow * DD + quad * 8);
    const short8 qa1 = *reinterpret_cast<const short8*>(Q + (size_t)qrow * DD + 32 + quad * 8);
    const short8 qa2 = *reinterpret_cast<const short8*>(Q + (size_t)(qrow + 16) * DD + quad * 8);
    const short8 qa3 = *reinterpret_cast<const short8*>(Q + (size_t)(qrow + 16) * DD + 32 + quad * 8);

    const int swz = l15 & 7;

    // DMA source map (8-row issues): lane covers row rb+(lane>>3),
    // source granule (lane&7)^(lane>>3); linear dest realizes slot=g^(row&7).
    const int srow = lane >> 3;
    const int sg   = ((lane & 7) ^ srow) * 8;

    float l0 = 0.f, l1 = 0.f;
    floatx4 acc0[4] = {}, acc1[4] = {};

    // Prologue: stage tile 0 into buffer 0 (4 DMA issues per wave)
    #pragma unroll
    for (int p = 0; p < 2; ++p) {
        const int rb = wave * 16 + p * 8;
        gl_lds16(K + (size_t)(rb + srow) * DD + sg, &Ks[0][rb * 64]);
        gl_lds16(VT + (size_t)(rb + srow) * SS + sg, &Vs[0][rb * 64]);
    }
    __asm__ volatile("s_waitcnt vmcnt(0) lgkmcnt(0)" ::: "memory");
    __builtin_amdgcn_s_barrier();   // tile 0 + Ms visible to all waves

    for (int t = 0; t < SS / 64; ++t) {
        const int cur = t & 1;

        // Prefetch next tile into the other buffer; flies under this tile's compute.
        if (t + 1 < SS / 64) {
            const int kn = (t + 1) * 64;
            #pragma unroll
            for (int p = 0; p < 2; ++p) {
                const int rb = wave * 16 + p * 8;
                gl_lds16(K + (size_t)(kn + rb + srow) * DD + sg, &Ks[cur ^ 1][rb * 64]);
                gl_lds16(VT + (size_t)(rb + srow) * SS + kn + sg, &Vs[cur ^ 1][rb * 64]);
            }
        }
        const int kt = t * 64;

        // QK^T: each K fragment read feeds both q column blocks (2x MFMA per read)
        floatx4 s0[4], s1[4];
        __builtin_amdgcn_s_setprio(1);
        #pragma unroll
        for (int f = 0; f < 4; ++f) {
            const int krow = (f * 16 + l15) * 64;
            const short8 ka = *reinterpret_cast<const short8*>(&Ks[cur][krow + (quad ^ swz) * 8]);
            const short8 kb = *reinterpret_cast<const short8*>(&Ks[cur][krow + ((quad + 4) ^ swz) * 8]);
            floatx4 z = {};
            z = __builtin_amdgcn_mfma_f32_16x16x32_bf16(ka, qa0, z, 0, 0, 0);
            z = __builtin_amdgcn_mfma_f32_16x16x32_bf16(kb, qa1, z, 0, 0, 0);
            s0[f] = z;
            floatx4 w = {};
            w = __builtin_amdgcn_mfma_f32_16x16x32_bf16(ka, qa2, w, 0, 0, 0);
            w = __builtin_amdgcn_mfma_f32_16x16x32_bf16(kb, qa3, w, 0, 0, 0);
            s1[f] = w;
        }
        __builtin_amdgcn_s_setprio(0);

        // Softmax numerator + pack to bf16 P (per-wave LDS transpose)
        #pragma unroll
        for (int f = 0; f < 4; ++f) {
            const float4 mf = *reinterpret_cast<const float4*>(&Ms[kt + f * 16 + quad * 4]);
            const float e00 = fast_exp2(s0[f][0]) * mf.x;
            const float e01 = fast_exp2(s0[f][1]) * mf.y;
            const float e02 = fast_exp2(s0[f][2]) * mf.z;
            const float e03 = fast_exp2(s0[f][3]) * mf.w;
            const float e10 = fast_exp2(s1[f][0]) * mf.x;
            const float e11 = fast_exp2(s1[f][1]) * mf.y;
            const float e12 = fast_exp2(s1[f][2]) * mf.z;
            const float e13 = fast_exp2(s1[f][3]) * mf.w;
            l0 += e00 + e01 + e02 + e03;
            l1 += e10 + e11 + e12 + e13;
            const int slot = ((2 * f + (quad >> 1)) ^ swz) * 8 + (quad & 1) * 4;
            uint2 p0; p0.x = pkbf(e00, e01); p0.y = pkbf(e02, e03);
            uint2 p1; p1.x = pkbf(e10, e11); p1.y = pkbf(e12, e13);
            *reinterpret_cast<uint2*>(pw0 + l15 * 64 + slot) = p0;
            *reinterpret_cast<uint2*>(pw1 + l15 * 64 + slot) = p1;
        }
        __asm__ volatile("s_waitcnt lgkmcnt(0)" ::: "memory");  // wave-local P drain

        const short8 pa0 = *reinterpret_cast<const short8*>(pw0 + l15 * 64 + (quad ^ swz) * 8);
        const short8 pa1 = *reinterpret_cast<const short8*>(pw0 + l15 * 64 + ((quad + 4) ^ swz) * 8);
        const short8 pb0 = *reinterpret_cast<const short8*>(pw1 + l15 * 64 + (quad ^ swz) * 8);
        const short8 pb1 = *reinterpret_cast<const short8*>(pw1 + l15 * 64 + ((quad + 4) ^ swz) * 8);

        // PV: each V fragment read feeds both q column blocks
        __builtin_amdgcn_s_setprio(1);
        #pragma unroll
        for (int nt = 0; nt < 4; ++nt) {
            const int vrow = (nt * 16 + l15) * 64;
            const short8 vb0 = *reinterpret_cast<const short8*>(&Vs[cur][vrow + (quad ^ swz) * 8]);
            const short8 vb1 = *reinterpret_cast<const short8*>(&Vs[cur][vrow + ((quad + 4) ^ swz) * 8]);
            acc0[nt] = __builtin_amdgcn_mfma_f32_16x16x32_bf16(pa0, vb0, acc0[nt], 0, 0, 0);
            acc0[nt] = __builtin_amdgcn_mfma_f32_16x16x32_bf16(pa1, vb1, acc0[nt], 0, 0, 0);
            acc1[nt] = __builtin_amdgcn_mfma_f32_16x16x32_bf16(pb0, vb0, acc1[nt], 0, 0, 0);
            acc1[nt] = __builtin_amdgcn_mfma_f32_16x16x32_bf16(pb1, vb1, acc1[nt], 0, 0, 0);
        }
        __builtin_amdgcn_s_setprio(0);

        // Pipeline turn: prefetched DMAs (issued at loop top) have had the whole
        // compute phase to land -> this drain is near-free. Single raw barrier
        // does double duty: WAR (all waves done reading buf[cur]) + staging
        // visibility (all waves' next-tile DMAs drained).
        if (t + 1 < SS / 64) {
            __asm__ volatile("s_waitcnt vmcnt(0)" ::: "memory");
            __builtin_amdgcn_s_barrier();
        }
    }

    // Softmax denominators: reduce across quads, redistribute per output row
    l0 += __shfl_xor(l0, 16, 64); l0 += __shfl_xor(l0, 32, 64);
    l1 += __shfl_xor(l1, 16, 64); l1 += __shfl_xor(l1, 32, 64);
    float i0[4], i1[4];
    #pragma unroll
    for (int r = 0; r < 4; ++r) {
        i0[r] = 1.f / __shfl(l0, quad * 4 + r, 16);
        i1[r] = 1.f / __shfl(l1, quad * 4 + r, 16);
    }

    const size_t obase = (size_t)bh * SS * DD;
    #pragma unroll
    for (int nt = 0; nt < 4; ++nt)
        #pragma unroll
        for (int r = 0; r < 4; ++r) {
            const int qq = q0 + wave * 32 + quad * 4 + r;
            const int d  = nt * 16 + l15;
            out[obase + (size_t)qq * DD + d] = acc0[nt][r] * i0[r];
            out[obase + (size_t)(qq + 16) * DD + d] = acc1[nt][r] * i1[r];
        }
}

extern "C" void kernel_launch(void* const* d_in, const int* in_sizes, int n_in,
                              void* d_out, int out_size, void* d_ws, size_t ws_size,
                              hipStream_t stream) {
    const float* q    = (const float*)d_in[0];
    const float* k    = (const float*)d_in[1];
    const float* v    = (const float*)d_in[2];
    const int*   mask = (const int*)d_in[3];
    const float* Wq   = (const float*)d_in[4];
    const float* bq   = (const float*)d_in[5];
    const float* Wk   = (const float*)d_in[6];
    const float* bk   = (const float*)d_in[7];
    const float* Wv   = (const float*)d_in[8];
    const float* bv   = (const float*)d_in[9];
    float* out = (float*)d_out;

    // Workspace (shorts): qws | kws | vtws | Xbf(3) | Wbf(3)
    __hip_bfloat16* qws  = (__hip_bfloat16*)d_ws;
    __hip_bfloat16* kws  = qws + (size_t)CX;
    __hip_bfloat16* vtws = kws + (size_t)CX;
    __hip_bfloat16* xb   = vtws + (size_t)CX;
    __hip_bfloat16* wb   = xb + (size_t)3 * CX;

    const int cvt_blocks = (3 * CX + 3 * CW) / (256 * 8);
    convert_kernel<<<dim3(cvt_blocks), 256, 0, stream>>>(q, k, v, Wq, Wk, Wv, xb, wb);
    proj_gemm<<<dim3(MM / 128, EE / 128, 3), 256, 0, stream>>>(
        xb, wb, bq, bk, bv, qws, kws, vtws);
    attn_kernel<<<dim3(SS / 128, BB * HH), 256, 0, stream>>>(
        qws, kws, vtws, mask, out);
}

// Round 2
// 203.075 us; speedup vs baseline: 1.0593x; 1.0397x over previous
//
#include <hip/hip_runtime.h>
#include <hip/hip_bf16.h>

// Problem constants
constexpr int BB = 2;
constexpr int SS = 2048;
constexpr int EE = 1024;
constexpr int HH = 16;
constexpr int DD = 64;
constexpr int MM = BB * SS;              // 4096 rows in the projection GEMMs
constexpr int CX = MM * EE;              // 4194304 elems per X slice (2^22)
constexpr int CW = EE * EE;              // 1048576 elems per W slice (2^20)
// Q pre-scale: 1/sqrt(EMBED_DIM) * log2(e) so attention scores are base-2 logits
#define QSCALE 0.045084220027780106f

typedef __attribute__((ext_vector_type(8))) short short8;    // 8 bf16 = 4 VGPRs (MFMA A/B frag)
typedef __attribute__((ext_vector_type(4))) float floatx4;   // MFMA C/D frag
typedef __attribute__((ext_vector_type(4))) unsigned uintx4; // 4 packed bf16 pairs

union fragu { uintx4 u; short8 s; };

__device__ inline short bf16bits(float x) {
    __hip_bfloat16 h = __float2bfloat16(x);
    return *reinterpret_cast<short*>(&h);
}

__device__ inline unsigned pkbf(float a, float b) {
    return (unsigned)(unsigned short)bf16bits(a) |
           ((unsigned)(unsigned short)bf16bits(b) << 16);
}

__device__ inline float fast_exp2(float x) {
#if __has_builtin(__builtin_amdgcn_exp2f)
    return __builtin_amdgcn_exp2f(x);
#else
    return exp2f(x);
#endif
}

// Async global->LDS, 16 B per lane. LDS dest = wave-uniform base + lane*16.
__device__ inline void gl_lds16(const __hip_bfloat16* g, const short* l) {
    __builtin_amdgcn_global_load_lds(
        (const __attribute__((address_space(1))) void*)g,
        (__attribute__((address_space(3))) void*)l, 16, 0, 0);
}

// Key relabeling so the post-exp QK score fragment IS the PV A-fragment:
// LDS K row p holds global key sigma(p).
// p = [f1 f0 q1 q0 r1 r0]  ->  sigma = [f1 q1 q0 f0 r1 r0]
__device__ inline int sigma_row(int p) {
    return (p & 0x23) | ((p & 0x0C) << 1) | ((p & 0x10) >> 2);
}

// ---------------------------------------------------------------------------
// Convert pass: f32 -> bf16, flat over 3 X slices then 3 W slices. (unchanged)
// ---------------------------------------------------------------------------
__global__ __launch_bounds__(256) void convert_kernel(
    const float* __restrict__ x0, const float* __restrict__ x1, const float* __restrict__ x2,
    const float* __restrict__ w0, const float* __restrict__ w1, const float* __restrict__ w2,
    __hip_bfloat16* __restrict__ xb, __hip_bfloat16* __restrict__ wb)
{
    const long long e = (long long)(blockIdx.x * 256 + threadIdx.x) * 8;
    const float* src;
    __hip_bfloat16* dst;
    if (e < 3LL * CX) {
        const int z = (int)(e >> 22);
        const int off = (int)(e & (CX - 1));
        src = ((z == 0) ? x0 : (z == 1) ? x1 : x2) + off;
        dst = xb + e;
    } else {
        const long long e2 = e - 3LL * CX;
        const int z = (int)(e2 >> 20);
        const int off = (int)(e2 & (CW - 1));
        src = ((z == 0) ? w0 : (z == 1) ? w1 : w2) + off;
        dst = wb + e2;
    }
    const float4 a = reinterpret_cast<const float4*>(src)[0];
    const float4 b = reinterpret_cast<const float4*>(src)[1];
    short8 r;
    r[0] = bf16bits(a.x); r[1] = bf16bits(a.y); r[2] = bf16bits(a.z); r[3] = bf16bits(a.w);
    r[4] = bf16bits(b.x); r[5] = bf16bits(b.y); r[6] = bf16bits(b.z); r[7] = bf16bits(b.w);
    *reinterpret_cast<short8*>(dst) = r;
}

// ---------------------------------------------------------------------------
// Projection GEMM (unchanged, best measured): 128x128 tile, BK=32,
// 256 threads, 2-barrier K-loop, async global_load_lds, superrow swizzle.
// which==0 output (Q) pre-scaled by QSCALE. V stored transposed [B,H,D,S].
// ---------------------------------------------------------------------------
__global__ __launch_bounds__(256) void proj_gemm(
    const __hip_bfloat16* __restrict__ xb,
    const __hip_bfloat16* __restrict__ wb,
    const float* __restrict__ bq, const float* __restrict__ bk, const float* __restrict__ bv,
    __hip_bfloat16* __restrict__ qws,
    __hip_bfloat16* __restrict__ kws,
    __hip_bfloat16* __restrict__ vtws)
{
    const int which = blockIdx.z;
    const __hip_bfloat16* A = xb + (size_t)which * CX;
    const __hip_bfloat16* W = wb + (size_t)which * CW;
    const float* bias = (which == 0) ? bq : (which == 1) ? bk : bv;

    const int m0   = blockIdx.x * 128;
    const int n0   = blockIdx.y * 128;
    const int tid  = threadIdx.x;
    const int wave = tid >> 6;
    const int lane = tid & 63;
    const int l15  = lane & 15;
    const int quad = lane >> 4;
    const int wr   = wave >> 1;
    const int wc   = wave & 1;

    __shared__ __align__(16) short As[128 * 32];   // 8 KiB, superrow-swizzled
    __shared__ __align__(16) short Bs[128 * 32];   // 8 KiB

    const int dpos  = (lane & 7) ^ (lane >> 3);
    const int drloc = 2 * (lane >> 3) + (dpos >> 2);
    const int dgran = (dpos & 3) * 8;              // k-offset in shorts

    const int rbase = (l15 >> 1) * 64;             // superrow offset within tile
    const int rslot = (((l15 & 1) * 4 + quad) ^ (l15 >> 1)) * 8;

    floatx4 acc[4][4] = {};

    for (int k0 = 0; k0 < EE; k0 += 32) {
        __syncthreads();  // WAR: previous iteration's frag reads complete
        #pragma unroll
        for (int p = 0; p < 2; ++p) {
            const int rb16 = wave * 32 + p * 16;   // 16-row issue base
            gl_lds16(A + (size_t)(m0 + rb16 + drloc) * EE + k0 + dgran, &As[rb16 * 32]);
            gl_lds16(W + (size_t)(n0 + rb16 + drloc) * EE + k0 + dgran, &Bs[rb16 * 32]);
        }
        __syncthreads();  // staging visible (drains vmcnt)

        short8 af[4], bf[4];
        #pragma unroll
        for (int mt = 0; mt < 4; ++mt)
            af[mt] = *reinterpret_cast<const short8*>(
                &As[(wr * 32 + mt * 8) * 64 + rbase + rslot]);
        #pragma unroll
        for (int nt = 0; nt < 4; ++nt)
            bf[nt] = *reinterpret_cast<const short8*>(
                &Bs[(wc * 32 + nt * 8) * 64 + rbase + rslot]);

        #pragma unroll
        for (int mt = 0; mt < 4; ++mt)
            #pragma unroll
            for (int nt = 0; nt < 4; ++nt)
                acc[mt][nt] = __builtin_amdgcn_mfma_f32_16x16x32_bf16(af[mt], bf[nt], acc[mt][nt], 0, 0, 0);
    }

    // Epilogue: C/D layout col = lane&15, row = quad*4 + r
    #pragma unroll
    for (int nt = 0; nt < 4; ++nt) {
        const int n = n0 + wc * 64 + nt * 16 + l15;
        const float bval = bias[n];
        const int h = n >> 6, d = n & 63;
        #pragma unroll
        for (int mt = 0; mt < 4; ++mt) {
            #pragma unroll
            for (int r = 0; r < 4; ++r) {
                const int m = m0 + wr * 64 + mt * 16 + quad * 4 + r;
                const int b = m >> 11;
                const int s = m & (SS - 1);
                float val = acc[mt][nt][r] + bval;
                if (which == 0) val *= QSCALE;   // fold softmax scale+log2e into Q
                const __hip_bfloat16 hv = __float2bfloat16(val);
                if (which == 0)
                    qws[(((size_t)b * HH + h) * SS + s) * DD + d] = hv;
                else if (which == 1)
                    kws[(((size_t)b * HH + h) * SS + s) * DD + d] = hv;
                else
                    vtws[(((size_t)b * HH + h) * DD + d) * SS + s] = hv;
            }
        }
    }
}

// ---------------------------------------------------------------------------
// Flash attention v3: P never touches LDS. K is staged with a key-relabeling
// row permutation sigma (source-address-only; DMA dest stays linear) chosen
// so that the QK^T score fragment, after exp2+mask+bf16-pack, is EXACTLY the
// PV A-operand fragment in-register. V keys stay linear (sigma cancels:
// slot k <-> key k). This removes the per-tile P LDS round-trip
// (8 ds_write_b64 + lgkmcnt(0) full-stop + 4 ds_read_b128 + 2^21 bank
// conflicts) from the critical path and cuts LDS 57->41 KB.
// Softmax denominator is permutation-invariant; mask reads use the permuted
// base 32*(f>>1)+8*quad+4*(f&1) (still contiguous float4).
// Same dbuf 1-barrier pipeline, XCD-aware head partition, 32 q-rows/wave.
// ---------------------------------------------------------------------------
__global__ __launch_bounds__(256) void attn_kernel(
    const __hip_bfloat16* __restrict__ qws,
    const __hip_bfloat16* __restrict__ kws,
    const __hip_bfloat16* __restrict__ vtws,
    const int* __restrict__ amask,
    float* __restrict__ out)
{
    const int flatb = blockIdx.y * gridDim.x + blockIdx.x;     // 0..511
    const int bh    = 4 * (flatb & 7) + ((flatb >> 3) & 3);    // XCD-partitioned head
    const int b     = bh >> 4;
    const int q0    = (flatb >> 5) * 128;
    const int tid  = threadIdx.x;
    const int wave = tid >> 6;
    const int lane = tid & 63;
    const int l15  = lane & 15;
    const int quad = lane >> 4;

    const __hip_bfloat16* Q  = qws  + (size_t)bh * SS * DD;
    const __hip_bfloat16* K  = kws  + (size_t)bh * SS * DD;
    const __hip_bfloat16* VT = vtws + (size_t)bh * DD * SS;
    const int* msk = amask + b * SS;

    __shared__ __align__(16) short Ks[2][64 * 64];   // 16 KiB, [row p][d] (key sigma(p)), dbuf
    __shared__ __align__(16) short Vs[2][64 * 64];   // 16 KiB, [d][key] swizzled, dbuf
    __shared__ __align__(16) float Ms[SS];           // 8 KiB, mask as {0,1} floats

    // Stage mask once: int {0,1} -> float {0,1} (multiplied in post-exp2)
    #pragma unroll
    for (int i = 0; i < 2; ++i) {
        const int j = tid + i * 256;
        const int4 m4 = reinterpret_cast<const int4*>(msk)[j];
        float4 f4;
        f4.x = (float)m4.x; f4.y = (float)m4.y; f4.z = (float)m4.z; f4.w = (float)m4.w;
        reinterpret_cast<float4*>(Ms)[j] = f4;
    }

    // Q fragments for two 16-row column blocks (32 q-rows per wave), in regs
    const int qrow = q0 + wave * 32 + l15;
    const short8 qa0 = *reinterpret_cast<const short8*>(Q + (size_t)qrow * DD + quad * 8);
    const short8 qa1 = *reinterpret_cast<const short8*>(Q + (size_t)qrow * DD + 32 + quad * 8);
    const short8 qa2 = *reinterpret_cast<const short8*>(Q + (size_t)(qrow + 16) * DD + quad * 8);
    const short8 qa3 = *reinterpret_cast<const short8*>(Q + (size_t)(qrow + 16) * DD + 32 + quad * 8);

    const int swz = l15 & 7;

    // DMA source map (8-row issues): lane covers LDS row rb+(lane>>3),
    // source granule (lane&7)^(lane>>3); linear dest realizes slot=g^(row&7).
    // K additionally applies the sigma key relabeling to the source ROW only.
    const int srow = lane >> 3;
    const int sg   = ((lane & 7) ^ srow) * 8;
    const int sk0  = sigma_row(wave * 16 + srow);        // issue 0 source key row
    const int sk1  = sigma_row(wave * 16 + 8 + srow);    // issue 1 source key row

    float l0 = 0.f, l1 = 0.f;
    floatx4 acc0[4] = {}, acc1[4] = {};

    // Prologue: stage tile 0 into buffer 0 (4 DMA issues per wave)
    {
        const int rb0 = wave * 16, rb1 = rb0 + 8;
        gl_lds16(K + (size_t)sk0 * DD + sg, &Ks[0][rb0 * 64]);
        gl_lds16(VT + (size_t)(rb0 + srow) * SS + sg, &Vs[0][rb0 * 64]);
        gl_lds16(K + (size_t)sk1 * DD + sg, &Ks[0][rb1 * 64]);
        gl_lds16(VT + (size_t)(rb1 + srow) * SS + sg, &Vs[0][rb1 * 64]);
    }
    __asm__ volatile("s_waitcnt vmcnt(0) lgkmcnt(0)" ::: "memory");
    __builtin_amdgcn_s_barrier();   // tile 0 + Ms visible to all waves

    for (int t = 0; t < SS / 64; ++t) {
        const int cur = t & 1;

        // Prefetch next tile into the other buffer; flies under this tile's compute.
        if (t + 1 < SS / 64) {
            const int kn = (t + 1) * 64;
            const int rb0 = wave * 16, rb1 = rb0 + 8;
            gl_lds16(K + (size_t)(kn + sk0) * DD + sg, &Ks[cur ^ 1][rb0 * 64]);
            gl_lds16(VT + (size_t)(rb0 + srow) * SS + kn + sg, &Vs[cur ^ 1][rb0 * 64]);
            gl_lds16(K + (size_t)(kn + sk1) * DD + sg, &Ks[cur ^ 1][rb1 * 64]);
            gl_lds16(VT + (size_t)(rb1 + srow) * SS + kn + sg, &Vs[cur ^ 1][rb1 * 64]);
        }
        const int kt = t * 64;

        // QK^T: each K fragment read feeds both q column blocks (2x MFMA per read)
        floatx4 s0[4], s1[4];
        __builtin_amdgcn_s_setprio(1);
        #pragma unroll
        for (int f = 0; f < 4; ++f) {
            const int krow = (f * 16 + l15) * 64;
            const short8 ka = *reinterpret_cast<const short8*>(&Ks[cur][krow + (quad ^ swz) * 8]);
            const short8 kb = *reinterpret_cast<const short8*>(&Ks[cur][krow + ((quad + 4) ^ swz) * 8]);
            floatx4 z = {};
            z = __builtin_amdgcn_mfma_f32_16x16x32_bf16(ka, qa0, z, 0, 0, 0);
            z = __builtin_amdgcn_mfma_f32_16x16x32_bf16(kb, qa1, z, 0, 0, 0);
            s0[f] = z;
            floatx4 w = {};
            w = __builtin_amdgcn_mfma_f32_16x16x32_bf16(ka, qa2, w, 0, 0, 0);
            w = __builtin_amdgcn_mfma_f32_16x16x32_bf16(kb, qa3, w, 0, 0, 0);
            s1[f] = w;
        }
        __builtin_amdgcn_s_setprio(0);

        // Softmax numerator + pack: lane's 16 masked exp values for q=l15 are
        // key-slots {8*quad..8*quad+7} (f=0,1) and {32+8*quad..+7} (f=2,3)
        // under sigma -> directly the PV A-fragment pair (pa0, pa1).
        fragu fa0, fa1, fb0, fb1;
        #pragma unroll
        for (int f = 0; f < 4; ++f) {
            const float4 mf = *reinterpret_cast<const float4*>(
                &Ms[kt + 32 * (f >> 1) + 8 * quad + 4 * (f & 1)]);
            const float e00 = fast_exp2(s0[f][0]) * mf.x;
            const float e01 = fast_exp2(s0[f][1]) * mf.y;
            const float e02 = fast_exp2(s0[f][2]) * mf.z;
            const float e03 = fast_exp2(s0[f][3]) * mf.w;
            const float e10 = fast_exp2(s1[f][0]) * mf.x;
            const float e11 = fast_exp2(s1[f][1]) * mf.y;
            const float e12 = fast_exp2(s1[f][2]) * mf.z;
            const float e13 = fast_exp2(s1[f][3]) * mf.w;
            l0 += e00 + e01 + e02 + e03;
            l1 += e10 + e11 + e12 + e13;
            uintx4& da = (f < 2) ? fa0.u : fa1.u;
            uintx4& db = (f < 2) ? fb0.u : fb1.u;
            const int i0 = (f & 1) * 2;
            da[i0]     = pkbf(e00, e01);
            da[i0 + 1] = pkbf(e02, e03);
            db[i0]     = pkbf(e10, e11);
            db[i0 + 1] = pkbf(e12, e13);
        }

        // PV: P fragments straight from registers; V fragment reads feed both halves
        __builtin_amdgcn_s_setprio(1);
        #pragma unroll
        for (int nt = 0; nt < 4; ++nt) {
            const int vrow = (nt * 16 + l15) * 64;
            const short8 vb0 = *reinterpret_cast<const short8*>(&Vs[cur][vrow + (quad ^ swz) * 8]);
            const short8 vb1 = *reinterpret_cast<const short8*>(&Vs[cur][vrow + ((quad + 4) ^ swz) * 8]);
            acc0[nt] = __builtin_amdgcn_mfma_f32_16x16x32_bf16(fa0.s, vb0, acc0[nt], 0, 0, 0);
            acc0[nt] = __builtin_amdgcn_mfma_f32_16x16x32_bf16(fa1.s, vb1, acc0[nt], 0, 0, 0);
            acc1[nt] = __builtin_amdgcn_mfma_f32_16x16x32_bf16(fb0.s, vb0, acc1[nt], 0, 0, 0);
            acc1[nt] = __builtin_amdgcn_mfma_f32_16x16x32_bf16(fb1.s, vb1, acc1[nt], 0, 0, 0);
        }
        __builtin_amdgcn_s_setprio(0);

        // Pipeline turn: prefetched DMAs had the whole compute phase to land.
        if (t + 1 < SS / 64) {
            __asm__ volatile("s_waitcnt vmcnt(0)" ::: "memory");
            __builtin_amdgcn_s_barrier();
        }
    }

    // Softmax denominators: reduce across quads, redistribute per output row
    l0 += __shfl_xor(l0, 16, 64); l0 += __shfl_xor(l0, 32, 64);
    l1 += __shfl_xor(l1, 16, 64); l1 += __shfl_xor(l1, 32, 64);
    float i0[4], i1[4];
    #pragma unroll
    for (int r = 0; r < 4; ++r) {
        i0[r] = 1.f / __shfl(l0, quad * 4 + r, 16);
        i1[r] = 1.f / __shfl(l1, quad * 4 + r, 16);
    }

    const size_t obase = (size_t)bh * SS * DD;
    #pragma unroll
    for (int nt = 0; nt < 4; ++nt)
        #pragma unroll
        for (int r = 0; r < 4; ++r) {
            const int qq = q0 + wave * 32 + quad * 4 + r;
            const int d  = nt * 16 + l15;
            out[obase + (size_t)qq * DD + d] = acc0[nt][r] * i0[r];
            out[obase + (size_t)(qq + 16) * DD + d] = acc1[nt][r] * i1[r];
        }
}

extern "C" void kernel_launch(void* const* d_in, const int* in_sizes, int n_in,
                              void* d_out, int out_size, void* d_ws, size_t ws_size,
                              hipStream_t stream) {
    const float* q    = (const float*)d_in[0];
    const float* k    = (const float*)d_in[1];
    const float* v    = (const float*)d_in[2];
    const int*   mask = (const int*)d_in[3];
    const float* Wq   = (const float*)d_in[4];
    const float* bq   = (const float*)d_in[5];
    const float* Wk   = (const float*)d_in[6];
    const float* bk   = (const float*)d_in[7];
    const float* Wv   = (const float*)d_in[8];
    const float* bv   = (const float*)d_in[9];
    float* out = (float*)d_out;

    // Workspace (shorts): qws | kws | vtws | Xbf(3) | Wbf(3)
    __hip_bfloat16* qws  = (__hip_bfloat16*)d_ws;
    __hip_bfloat16* kws  = qws + (size_t)CX;
    __hip_bfloat16* vtws = kws + (size_t)CX;
    __hip_bfloat16* xb   = vtws + (size_t)CX;
    __hip_bfloat16* wb   = xb + (size_t)3 * CX;

    const int cvt_blocks = (3 * CX + 3 * CW) / (256 * 8);
    convert_kernel<<<dim3(cvt_blocks), 256, 0, stream>>>(q, k, v, Wq, Wk, Wv, xb, wb);
    proj_gemm<<<dim3(MM / 128, EE / 128, 3), 256, 0, stream>>>(
        xb, wb, bq, bk, bv, qws, kws, vtws);
    attn_kernel<<<dim3(SS / 128, BB * HH), 256, 0, stream>>>(
        qws, kws, vtws, mask, out);
}

// Round 3
// 202.411 us; speedup vs baseline: 1.0628x; 1.0033x over previous
//
#include <hip/hip_runtime.h>
#include <hip/hip_bf16.h>

// Problem constants
constexpr int BB = 2;
constexpr int SS = 2048;
constexpr int EE = 1024;
constexpr int HH = 16;
constexpr int DD = 64;
constexpr int MM = BB * SS;              // 4096 rows in the projection GEMMs
constexpr int CX = MM * EE;              // 4194304 elems per X slice (2^22)
constexpr int CW = EE * EE;              // 1048576 elems per W slice (2^20)
// Q pre-scale: 1/sqrt(EMBED_DIM) * log2(e) so attention scores are base-2 logits
#define QSCALE 0.045084220027780106f

typedef __attribute__((ext_vector_type(8))) short short8;    // 8 bf16 = 4 VGPRs (MFMA A/B frag)
typedef __attribute__((ext_vector_type(4))) float floatx4;   // MFMA C/D frag
typedef __attribute__((ext_vector_type(4))) unsigned uintx4; // 4 packed bf16 pairs

union fragu { uintx4 u; short8 s; };

__device__ inline short bf16bits(float x) {
    __hip_bfloat16 h = __float2bfloat16(x);
    return *reinterpret_cast<short*>(&h);
}

__device__ inline unsigned pkbf(float a, float b) {
    return (unsigned)(unsigned short)bf16bits(a) |
           ((unsigned)(unsigned short)bf16bits(b) << 16);
}

__device__ inline float fast_exp2(float x) {
#if __has_builtin(__builtin_amdgcn_exp2f)
    return __builtin_amdgcn_exp2f(x);
#else
    return exp2f(x);
#endif
}

// Async global->LDS, 16 B per lane. LDS dest = wave-uniform base + lane*16.
__device__ inline void gl_lds16(const __hip_bfloat16* g, const short* l) {
    __builtin_amdgcn_global_load_lds(
        (const __attribute__((address_space(1))) void*)g,
        (__attribute__((address_space(3))) void*)l, 16, 0, 0);
}

// Key relabeling so the post-exp QK score fragment IS the PV A-fragment:
// LDS K row p holds global key sigma(p).
// p = [f1 f0 q1 q0 r1 r0]  ->  sigma = [f1 q1 q0 f0 r1 r0]
__device__ inline int sigma_row(int p) {
    return (p & 0x23) | ((p & 0x0C) << 1) | ((p & 0x10) >> 2);
}

// ---------------------------------------------------------------------------
// Convert pass: f32 -> bf16, flat over 3 X slices then 3 W slices. (unchanged)
// ---------------------------------------------------------------------------
__global__ __launch_bounds__(256) void convert_kernel(
    const float* __restrict__ x0, const float* __restrict__ x1, const float* __restrict__ x2,
    const float* __restrict__ w0, const float* __restrict__ w1, const float* __restrict__ w2,
    __hip_bfloat16* __restrict__ xb, __hip_bfloat16* __restrict__ wb)
{
    const long long e = (long long)(blockIdx.x * 256 + threadIdx.x) * 8;
    const float* src;
    __hip_bfloat16* dst;
    if (e < 3LL * CX) {
        const int z = (int)(e >> 22);
        const int off = (int)(e & (CX - 1));
        src = ((z == 0) ? x0 : (z == 1) ? x1 : x2) + off;
        dst = xb + e;
    } else {
        const long long e2 = e - 3LL * CX;
        const int z = (int)(e2 >> 20);
        const int off = (int)(e2 & (CW - 1));
        src = ((z == 0) ? w0 : (z == 1) ? w1 : w2) + off;
        dst = wb + e2;
    }
    const float4 a = reinterpret_cast<const float4*>(src)[0];
    const float4 b = reinterpret_cast<const float4*>(src)[1];
    short8 r;
    r[0] = bf16bits(a.x); r[1] = bf16bits(a.y); r[2] = bf16bits(a.z); r[3] = bf16bits(a.w);
    r[4] = bf16bits(b.x); r[5] = bf16bits(b.y); r[6] = bf16bits(b.z); r[7] = bf16bits(b.w);
    *reinterpret_cast<short8*>(dst) = r;
}

// ---------------------------------------------------------------------------
// Projection GEMM v2: 128x128 tile, BK=32, 256 threads, async global_load_lds,
// superrow swizzle — now with 3-buffer depth-2 prefetch and COUNTED vmcnt(4)
// at the per-K-step barrier (T3/T4): each wave's 4 next-next-step DMAs stay
// in flight across the barrier, so staging latency is covered by ~2 compute
// phases instead of being drained every step. LDS 48 KB -> 3 blocks/CU
// (grid 768 = exactly 3/CU).
// which==0 output (Q) pre-scaled by QSCALE. V stored transposed [B,H,D,S].
// ---------------------------------------------------------------------------
__global__ __launch_bounds__(256) void proj_gemm(
    const __hip_bfloat16* __restrict__ xb,
    const __hip_bfloat16* __restrict__ wb,
    const float* __restrict__ bq, const float* __restrict__ bk, const float* __restrict__ bv,
    __hip_bfloat16* __restrict__ qws,
    __hip_bfloat16* __restrict__ kws,
    __hip_bfloat16* __restrict__ vtws)
{
    const int which = blockIdx.z;
    const __hip_bfloat16* A = xb + (size_t)which * CX;
    const __hip_bfloat16* W = wb + (size_t)which * CW;
    const float* bias = (which == 0) ? bq : (which == 1) ? bk : bv;

    const int m0   = blockIdx.x * 128;
    const int n0   = blockIdx.y * 128;
    const int tid  = threadIdx.x;
    const int wave = tid >> 6;
    const int lane = tid & 63;
    const int l15  = lane & 15;
    const int quad = lane >> 4;
    const int wr   = wave >> 1;
    const int wc   = wave & 1;

    __shared__ __align__(16) short As[3][128 * 32];   // 24 KiB, superrow-swizzled, 3-buf
    __shared__ __align__(16) short Bs[3][128 * 32];   // 24 KiB

    const int dpos  = (lane & 7) ^ (lane >> 3);
    const int drloc = 2 * (lane >> 3) + (dpos >> 2);
    const int dgran = (dpos & 3) * 8;              // k-offset in shorts

    const int rbase = (l15 >> 1) * 64;             // superrow offset within tile
    const int rslot = (((l15 & 1) * 4 + quad) ^ (l15 >> 1)) * 8;

    floatx4 acc[4][4] = {};

    constexpr int NK = EE / 32;                    // 32 K-steps

    // Prologue: stage K-steps 0 and 1 into buffers 0,1 (8 DMA issues/wave)
    #pragma unroll
    for (int tt = 0; tt < 2; ++tt) {
        const int k0 = tt * 32;
        #pragma unroll
        for (int p = 0; p < 2; ++p) {
            const int rb16 = wave * 32 + p * 16;   // 16-row issue base
            gl_lds16(A + (size_t)(m0 + rb16 + drloc) * EE + k0 + dgran, &As[tt][rb16 * 32]);
            gl_lds16(W + (size_t)(n0 + rb16 + drloc) * EE + k0 + dgran, &Bs[tt][rb16 * 32]);
        }
    }
    __asm__ volatile("s_waitcnt vmcnt(4) lgkmcnt(0)" ::: "memory");  // step-0 staged
    __builtin_amdgcn_s_barrier();

    for (int t = 0; t < NK; ++t) {
        const int cur = t % 3;

        // Depth-2 prefetch: issue K-step t+2 into buffer (t+2)%3.
        if (t + 2 < NK) {
            const int nxt = (t + 2) % 3;
            const int k0 = (t + 2) * 32;
            #pragma unroll
            for (int p = 0; p < 2; ++p) {
                const int rb16 = wave * 32 + p * 16;
                gl_lds16(A + (size_t)(m0 + rb16 + drloc) * EE + k0 + dgran, &As[nxt][rb16 * 32]);
                gl_lds16(W + (size_t)(n0 + rb16 + drloc) * EE + k0 + dgran, &Bs[nxt][rb16 * 32]);
            }
        }

        short8 af[4], bf[4];
        #pragma unroll
        for (int mt = 0; mt < 4; ++mt)
            af[mt] = *reinterpret_cast<const short8*>(
                &As[cur][(wr * 32 + mt * 8) * 64 + rbase + rslot]);
        #pragma unroll
        for (int nt = 0; nt < 4; ++nt)
            bf[nt] = *reinterpret_cast<const short8*>(
                &Bs[cur][(wc * 32 + nt * 8) * 64 + rbase + rslot]);

        __builtin_amdgcn_s_setprio(1);
        #pragma unroll
        for (int mt = 0; mt < 4; ++mt)
            #pragma unroll
            for (int nt = 0; nt < 4; ++nt)
                acc[mt][nt] = __builtin_amdgcn_mfma_f32_16x16x32_bf16(af[mt], bf[nt], acc[mt][nt], 0, 0, 0);
        __builtin_amdgcn_s_setprio(0);

        // Counted pipeline turn: own t+2 loads (4) may stay in flight; oldest-4
        // semantics guarantee step t+1's staging has landed before the barrier.
        if (t + 1 < NK) {
            if (t + 2 < NK) { __asm__ volatile("s_waitcnt vmcnt(4)" ::: "memory"); }
            else            { __asm__ volatile("s_waitcnt vmcnt(0)" ::: "memory"); }
            __builtin_amdgcn_s_barrier();
        }
    }

    // Epilogue: C/D layout col = lane&15, row = quad*4 + r
    #pragma unroll
    for (int nt = 0; nt < 4; ++nt) {
        const int n = n0 + wc * 64 + nt * 16 + l15;
        const float bval = bias[n];
        const int h = n >> 6, d = n & 63;
        #pragma unroll
        for (int mt = 0; mt < 4; ++mt) {
            #pragma unroll
            for (int r = 0; r < 4; ++r) {
                const int m = m0 + wr * 64 + mt * 16 + quad * 4 + r;
                const int b = m >> 11;
                const int s = m & (SS - 1);
                float val = acc[mt][nt][r] + bval;
                if (which == 0) val *= QSCALE;   // fold softmax scale+log2e into Q
                const __hip_bfloat16 hv = __float2bfloat16(val);
                if (which == 0)
                    qws[(((size_t)b * HH + h) * SS + s) * DD + d] = hv;
                else if (which == 1)
                    kws[(((size_t)b * HH + h) * SS + s) * DD + d] = hv;
                else
                    vtws[(((size_t)b * HH + h) * DD + d) * SS + s] = hv;
            }
        }
    }
}

// ---------------------------------------------------------------------------
// Flash attention v4: v3 (sigma-permuted K so P stays in registers) +
//  (a) 3-buffer depth-2 DMA prefetch with COUNTED vmcnt(4) at the tile
//      barrier — each wave's 4 tile-(t+2) DMAs remain in flight; the
//      oldest-4 FIFO semantics of vmcnt guarantee tile t+1 has landed.
//      Staging latency now has ~2 compute phases to hide under.
//  (b) softmax denominator computed on the MFMA pipe: l = P · ones via
//      mfma(P_frag, ones_frag) — removes 16 VALU adds/tile and the
//      epilogue cross-lane shuffles; the D-fragment row=quad*4+r layout
//      matches the epilogue's per-row divide exactly.
// LDS 56 KB -> 2 blocks/CU (grid-limited to 2 anyway).
// ---------------------------------------------------------------------------
__global__ __launch_bounds__(256) void attn_kernel(
    const __hip_bfloat16* __restrict__ qws,
    const __hip_bfloat16* __restrict__ kws,
    const __hip_bfloat16* __restrict__ vtws,
    const int* __restrict__ amask,
    float* __restrict__ out)
{
    const int flatb = blockIdx.y * gridDim.x + blockIdx.x;     // 0..511
    const int bh    = 4 * (flatb & 7) + ((flatb >> 3) & 3);    // XCD-partitioned head
    const int b     = bh >> 4;
    const int q0    = (flatb >> 5) * 128;
    const int tid  = threadIdx.x;
    const int wave = tid >> 6;
    const int lane = tid & 63;
    const int l15  = lane & 15;
    const int quad = lane >> 4;

    const __hip_bfloat16* Q  = qws  + (size_t)bh * SS * DD;
    const __hip_bfloat16* K  = kws  + (size_t)bh * SS * DD;
    const __hip_bfloat16* VT = vtws + (size_t)bh * DD * SS;
    const int* msk = amask + b * SS;

    __shared__ __align__(16) short Ks[3][64 * 64];   // 24 KiB, [row p][d] (key sigma(p)), 3-buf
    __shared__ __align__(16) short Vs[3][64 * 64];   // 24 KiB, [d][key] swizzled, 3-buf
    __shared__ __align__(16) float Ms[SS];           // 8 KiB, mask as {0,1} floats

    // Stage mask once: int {0,1} -> float {0,1} (multiplied in post-exp2)
    #pragma unroll
    for (int i = 0; i < 2; ++i) {
        const int j = tid + i * 256;
        const int4 m4 = reinterpret_cast<const int4*>(msk)[j];
        float4 f4;
        f4.x = (float)m4.x; f4.y = (float)m4.y; f4.z = (float)m4.z; f4.w = (float)m4.w;
        reinterpret_cast<float4*>(Ms)[j] = f4;
    }

    // Q fragments for two 16-row column blocks (32 q-rows per wave), in regs
    const int qrow = q0 + wave * 32 + l15;
    const short8 qa0 = *reinterpret_cast<const short8*>(Q + (size_t)qrow * DD + quad * 8);
    const short8 qa1 = *reinterpret_cast<const short8*>(Q + (size_t)qrow * DD + 32 + quad * 8);
    const short8 qa2 = *reinterpret_cast<const short8*>(Q + (size_t)(qrow + 16) * DD + quad * 8);
    const short8 qa3 = *reinterpret_cast<const short8*>(Q + (size_t)(qrow + 16) * DD + 32 + quad * 8);

    const int swz = l15 & 7;

    // ones fragment (bf16 1.0) for the l = P*ones denominator MFMA
    short8 ones;
    #pragma unroll
    for (int i = 0; i < 8; ++i) ones[i] = (short)0x3F80;

    // DMA source map (8-row issues): lane covers LDS row rb+(lane>>3),
    // source granule (lane&7)^(lane>>3); linear dest realizes slot=g^(row&7).
    // K additionally applies the sigma key relabeling to the source ROW only.
    const int srow = lane >> 3;
    const int sg   = ((lane & 7) ^ srow) * 8;
    const int sk0  = sigma_row(wave * 16 + srow);        // issue 0 source key row
    const int sk1  = sigma_row(wave * 16 + 8 + srow);    // issue 1 source key row
    const int rb0  = wave * 16, rb1 = rb0 + 8;

    floatx4 acc0[4] = {}, acc1[4] = {};
    floatx4 accl0 = {}, accl1 = {};

    constexpr int NT = SS / 64;                          // 32 key tiles

    // Prologue: stage tiles 0 and 1 into buffers 0,1 (8 DMA issues/wave)
    #pragma unroll
    for (int tt = 0; tt < 2; ++tt) {
        const int kn = tt * 64;
        gl_lds16(K + (size_t)(kn + sk0) * DD + sg, &Ks[tt][rb0 * 64]);
        gl_lds16(VT + (size_t)(rb0 + srow) * SS + kn + sg, &Vs[tt][rb0 * 64]);
        gl_lds16(K + (size_t)(kn + sk1) * DD + sg, &Ks[tt][rb1 * 64]);
        gl_lds16(VT + (size_t)(rb1 + srow) * SS + kn + sg, &Vs[tt][rb1 * 64]);
    }
    __asm__ volatile("s_waitcnt vmcnt(4) lgkmcnt(0)" ::: "memory");  // tile 0 + Ms staged
    __builtin_amdgcn_s_barrier();

    for (int t = 0; t < NT; ++t) {
        const int cur = t % 3;

        // Depth-2 prefetch: issue tile t+2 into buffer (t+2)%3.
        if (t + 2 < NT) {
            const int nxt = (t + 2) % 3;
            const int kn = (t + 2) * 64;
            gl_lds16(K + (size_t)(kn + sk0) * DD + sg, &Ks[nxt][rb0 * 64]);
            gl_lds16(VT + (size_t)(rb0 + srow) * SS + kn + sg, &Vs[nxt][rb0 * 64]);
            gl_lds16(K + (size_t)(kn + sk1) * DD + sg, &Ks[nxt][rb1 * 64]);
            gl_lds16(VT + (size_t)(rb1 + srow) * SS + kn + sg, &Vs[nxt][rb1 * 64]);
        }
        const int kt = t * 64;

        // QK^T: each K fragment read feeds both q column blocks (2x MFMA per read)
        floatx4 s0[4], s1[4];
        __builtin_amdgcn_s_setprio(1);
        #pragma unroll
        for (int f = 0; f < 4; ++f) {
            const int krow = (f * 16 + l15) * 64;
            const short8 ka = *reinterpret_cast<const short8*>(&Ks[cur][krow + (quad ^ swz) * 8]);
            const short8 kb = *reinterpret_cast<const short8*>(&Ks[cur][krow + ((quad + 4) ^ swz) * 8]);
            floatx4 z = {};
            z = __builtin_amdgcn_mfma_f32_16x16x32_bf16(ka, qa0, z, 0, 0, 0);
            z = __builtin_amdgcn_mfma_f32_16x16x32_bf16(kb, qa1, z, 0, 0, 0);
            s0[f] = z;
            floatx4 w = {};
            w = __builtin_amdgcn_mfma_f32_16x16x32_bf16(ka, qa2, w, 0, 0, 0);
            w = __builtin_amdgcn_mfma_f32_16x16x32_bf16(kb, qa3, w, 0, 0, 0);
            s1[f] = w;
        }
        __builtin_amdgcn_s_setprio(0);

        // Softmax numerator + pack: lane's 16 masked exp values for q=l15 are
        // key-slots {8*quad..+7} (f=0,1) and {32+8*quad..+7} (f=2,3) under
        // sigma -> directly the PV A-fragment pairs.
        fragu fa0, fa1, fb0, fb1;
        #pragma unroll
        for (int f = 0; f < 4; ++f) {
            const float4 mf = *reinterpret_cast<const float4*>(
                &Ms[kt + 32 * (f >> 1) + 8 * quad + 4 * (f & 1)]);
            const float e00 = fast_exp2(s0[f][0]) * mf.x;
            const float e01 = fast_exp2(s0[f][1]) * mf.y;
            const float e02 = fast_exp2(s0[f][2]) * mf.z;
            const float e03 = fast_exp2(s0[f][3]) * mf.w;
            const float e10 = fast_exp2(s1[f][0]) * mf.x;
            const float e11 = fast_exp2(s1[f][1]) * mf.y;
            const float e12 = fast_exp2(s1[f][2]) * mf.z;
            const float e13 = fast_exp2(s1[f][3]) * mf.w;
            uintx4& da = (f < 2) ? fa0.u : fa1.u;
            uintx4& db = (f < 2) ? fb0.u : fb1.u;
            const int i0 = (f & 1) * 2;
            da[i0]     = pkbf(e00, e01);
            da[i0 + 1] = pkbf(e02, e03);
            db[i0]     = pkbf(e10, e11);
            db[i0 + 1] = pkbf(e12, e13);
        }

        // PV + denominator: P fragments straight from registers.
        __builtin_amdgcn_s_setprio(1);
        accl0 = __builtin_amdgcn_mfma_f32_16x16x32_bf16(fa0.s, ones, accl0, 0, 0, 0);
        accl0 = __builtin_amdgcn_mfma_f32_16x16x32_bf16(fa1.s, ones, accl0, 0, 0, 0);
        accl1 = __builtin_amdgcn_mfma_f32_16x16x32_bf16(fb0.s, ones, accl1, 0, 0, 0);
        accl1 = __builtin_amdgcn_mfma_f32_16x16x32_bf16(fb1.s, ones, accl1, 0, 0, 0);
        #pragma unroll
        for (int nt = 0; nt < 4; ++nt) {
            const int vrow = (nt * 16 + l15) * 64;
            const short8 vb0 = *reinterpret_cast<const short8*>(&Vs[cur][vrow + (quad ^ swz) * 8]);
            const short8 vb1 = *reinterpret_cast<const short8*>(&Vs[cur][vrow + ((quad + 4) ^ swz) * 8]);
            acc0[nt] = __builtin_amdgcn_mfma_f32_16x16x32_bf16(fa0.s, vb0, acc0[nt], 0, 0, 0);
            acc0[nt] = __builtin_amdgcn_mfma_f32_16x16x32_bf16(fa1.s, vb1, acc0[nt], 0, 0, 0);
            acc1[nt] = __builtin_amdgcn_mfma_f32_16x16x32_bf16(fb0.s, vb0, acc1[nt], 0, 0, 0);
            acc1[nt] = __builtin_amdgcn_mfma_f32_16x16x32_bf16(fb1.s, vb1, acc1[nt], 0, 0, 0);
        }
        __builtin_amdgcn_s_setprio(0);

        // Counted pipeline turn: own tile-(t+2) loads (4) may stay in flight;
        // oldest-4 semantics guarantee tile t+1's staging has landed.
        if (t + 1 < NT) {
            if (t + 2 < NT) { __asm__ volatile("s_waitcnt vmcnt(4)" ::: "memory"); }
            else            { __asm__ volatile("s_waitcnt vmcnt(0)" ::: "memory"); }
            __builtin_amdgcn_s_barrier();
        }
    }

    // Denominators: accl D-fragment row=quad*4+r equals l for that output row
    // (every column identical) — no cross-lane reduce needed.
    float i0[4], i1[4];
    #pragma unroll
    for (int r = 0; r < 4; ++r) {
        i0[r] = 1.f / accl0[r];
        i1[r] = 1.f / accl1[r];
    }

    const size_t obase = (size_t)bh * SS * DD;
    #pragma unroll
    for (int nt = 0; nt < 4; ++nt)
        #pragma unroll
        for (int r = 0; r < 4; ++r) {
            const int qq = q0 + wave * 32 + quad * 4 + r;
            const int d  = nt * 16 + l15;
            out[obase + (size_t)qq * DD + d] = acc0[nt][r] * i0[r];
            out[obase + (size_t)(qq + 16) * DD + d] = acc1[nt][r] * i1[r];
        }
}

extern "C" void kernel_launch(void* const* d_in, const int* in_sizes, int n_in,
                              void* d_out, int out_size, void* d_ws, size_t ws_size,
                              hipStream_t stream) {
    const float* q    = (const float*)d_in[0];
    const float* k    = (const float*)d_in[1];
    const float* v    = (const float*)d_in[2];
    const int*   mask = (const int*)d_in[3];
    const float* Wq   = (const float*)d_in[4];
    const float* bq   = (const float*)d_in[5];
    const float* Wk   = (const float*)d_in[6];
    const float* bk   = (const float*)d_in[7];
    const float* Wv   = (const float*)d_in[8];
    const float* bv   = (const float*)d_in[9];
    float* out = (float*)d_out;

    // Workspace (shorts): qws | kws | vtws | Xbf(3) | Wbf(3)
    __hip_bfloat16* qws  = (__hip_bfloat16*)d_ws;
    __hip_bfloat16* kws  = qws + (size_t)CX;
    __hip_bfloat16* vtws = kws + (size_t)CX;
    __hip_bfloat16* xb   = vtws + (size_t)CX;
    __hip_bfloat16* wb   = xb + (size_t)3 * CX;

    const int cvt_blocks = (3 * CX + 3 * CW) / (256 * 8);
    convert_kernel<<<dim3(cvt_blocks), 256, 0, stream>>>(q, k, v, Wq, Wk, Wv, xb, wb);
    proj_gemm<<<dim3(MM / 128, EE / 128, 3), 256, 0, stream>>>(
        xb, wb, bq, bk, bv, qws, kws, vtws);
    attn_kernel<<<dim3(SS / 128, BB * HH), 256, 0, stream>>>(
        qws, kws, vtws, mask, out);
}